// Round 2
// baseline (89.456 us; speedup 1.0000x reference)
//
#include <hip/hip_runtime.h>

// dissected Conv2d == standard 3x3 conv, NCHW, pad=1, fp32 in/out, bf16 MFMA inside.
// B=8, C_in=C_out=64, H=W=56.
//
// 3-kernel pipeline (all in d_ws scratch, re-done every call):
//   1. prep_x:   x (NCHW fp32) -> x_t (padded NHWC bf16 [8][58][58][64], zero border)
//   2. repack_w: w (OIHW fp32) -> MFMA A-fragment layout bf16 [s][wave][lane][8]
//   3. conv_main: implicit GEMM, no LDS: A frags in regs, B frags = contiguous
//      16B global loads from L2-resident x_t. 784 blocks x 4 waves.

typedef __attribute__((ext_vector_type(8))) short bf8_t;   // 8 bf16 (MFMA A/B frag)
typedef __attribute__((ext_vector_type(4))) float f4_t;    // MFMA C/D frag

#define IC 64
#define OC 64
#define HH 56
#define WW 56
#define NB 8
#define PH 58              // padded rows
#define PW 58              // padded cols
#define NS 18              // K-steps of 32 (K = 9 taps * 64 ic, tap-major)
#define NPIX (HH * WW)     // 3136 pixels per batch image
#define PT 98              // 32-pixel tiles per batch (98*32 = 3136 exact)

#define XT_BYTES (NB * PH * PW * IC * 2)   // 3,444,736 B (16B-aligned)
#define LPAD 68                             // LDS row pad for prep_x transpose

__device__ __forceinline__ unsigned short f2bf(float f) {
    unsigned u = __float_as_uint(f);
    return (unsigned short)((u + 0x7FFFu + ((u >> 16) & 1u)) >> 16);
}

// ---------------------------------------------------------------------------
// Kernel 1: NCHW fp32 -> padded NHWC bf16, zero border.
// Blocks 0..447: one (b,h) row each, LDS transpose. Blocks 448..455: border
// zeroing for batch b = bx-448.
// ---------------------------------------------------------------------------
__global__ __launch_bounds__(256)
void prep_x(const float* __restrict__ x, unsigned short* __restrict__ xt) {
    const int bx  = blockIdx.x;
    const int tid = threadIdx.x;
    if (bx < NB * HH) {
        const int b = bx / HH, h = bx - (bx / HH) * HH;
        __shared__ unsigned short lds[WW * LPAD];
        for (int idx = tid; idx < IC * WW; idx += 256) {
            const int ic = idx / WW, w = idx - (idx / WW) * WW;
            lds[w * LPAD + ic] = f2bf(x[((b * IC + ic) * HH + h) * WW + w]);
        }
        __syncthreads();
        // 896 items of 8B (w, ic-quad); writes contiguous 128B per 16 lanes
        for (int idx = tid; idx < WW * 16; idx += 256) {
            const int w = idx >> 4, icq = idx & 15;
            const uint2 v = *(const uint2*)&lds[w * LPAD + icq * 4];
            *(uint2*)&xt[((b * PH + h + 1) * PW + (w + 1)) * IC + icq * 4] = v;
        }
    } else {
        // zero the border of batch b: row 0, row 57, col 0, col 57
        const int b = bx - NB * HH;
        unsigned short* base = xt + (size_t)b * PH * PW * IC;
        for (int i = tid; i < 1824; i += 256) {   // 1824 chunks of 8 u16 (16B)
            int off;
            if (i < 464)        off = i * 8;                               // row 0
            else if (i < 928)   off = 57 * PW * IC + (i - 464) * 8;        // row 57
            else if (i < 1376) { int j = i - 928;  off = (1 + (j >> 3)) * PW * IC + (j & 7) * 8; }              // col 0
            else               { int j = i - 1376; off = (1 + (j >> 3)) * PW * IC + 57 * IC + (j & 7) * 8; }    // col 57
            *(uint4*)(base + off) = uint4{0, 0, 0, 0};
        }
    }
}

// ---------------------------------------------------------------------------
// Kernel 2: weights OIHW fp32 -> A-fragment bf16, layout [s][wv][lane][8].
// A-frag (16x16x32): lane holds A[row = lane&15][k = (lane>>4)*8 + j],
// global k = s*32 + klocal; k -> (tap = k/64, ic = k%64).
// ---------------------------------------------------------------------------
__global__ __launch_bounds__(256)
void repack_w(const float* __restrict__ w, unsigned short* __restrict__ wf) {
    const int s    = blockIdx.x;        // 0..17
    const int tid  = threadIdx.x;
    const int wv   = tid >> 6;
    const int lane = tid & 63;
    const int oc   = wv * 16 + (lane & 15);
    const int kg   = lane >> 4;
    const int tap  = s >> 1;
    const int ic0  = (s & 1) * 32 + kg * 8;
    unsigned short tmp[8];
    #pragma unroll
    for (int j = 0; j < 8; ++j)
        tmp[j] = f2bf(w[(oc * IC + ic0 + j) * 9 + tap]);
    *(uint4*)&wf[(((s * 4 + wv) * 64) + lane) * 8] = *(const uint4*)tmp;
}

// ---------------------------------------------------------------------------
// Kernel 3: main conv. Grid 8*98 = 784 blocks x 256 thr (4 waves).
// Wave wv: oc [16wv, 16wv+16), 32 pixels (2 MFMA N-tiles), K=576 in 18 steps.
// No LDS: A frags live in 72 VGPRs, B frags are 16B contiguous loads of x_t.
// ---------------------------------------------------------------------------
__global__ __launch_bounds__(256)
void conv_main(const unsigned short* __restrict__ xt,
               const unsigned short* __restrict__ wf,
               const float* __restrict__ bias,
               float* __restrict__ out) {
    const int bx   = blockIdx.x;
    const int b    = bx / PT;
    const int pt   = bx - b * PT;
    const int p0   = pt * 32;
    const int tid  = threadIdx.x;
    const int wv   = tid >> 6;
    const int lane = tid & 63;
    const int kg   = lane >> 4;
    const int l15  = lane & 15;

    // A fragments: coalesced 1KB/wave per step, L2-hot (73.7KB total set)
    bf8_t afrag[NS];
    #pragma unroll
    for (int s = 0; s < NS; ++s)
        afrag[s] = *(const bf8_t*)&wf[(((s * 4 + wv) * 64) + lane) * 8];

    // per-pixel base addresses into padded x_t (tap (0,0) position)
    const char* pbase0;
    const char* pbase1;
    int pp0, pp1;
    {
        const int p = p0 + l15;
        const int hp = p / WW, wp = p - (p / WW) * WW;
        pp0 = p;
        pbase0 = (const char*)xt +
                 ((size_t)b * PH * PW * IC + ((hp * PW + wp) * IC) + kg * 8) * 2;
    }
    {
        const int p = p0 + 16 + l15;
        const int hp = p / WW, wp = p - (p / WW) * WW;
        pp1 = p;
        pbase1 = (const char*)xt +
                 ((size_t)b * PH * PW * IC + ((hp * PW + wp) * IC) + kg * 8) * 2;
    }

    f4_t acc0 = {0.f, 0.f, 0.f, 0.f};
    f4_t acc1 = {0.f, 0.f, 0.f, 0.f};

    #pragma unroll
    for (int s = 0; s < NS; ++s) {
        const int tap  = s >> 1;
        const int soff = ((tap / 3) * PW + (tap % 3)) * IC * 2 + (s & 1) * 64;
        const bf8_t bv0 = *(const bf8_t*)(pbase0 + soff);
        const bf8_t bv1 = *(const bf8_t*)(pbase1 + soff);
        acc0 = __builtin_amdgcn_mfma_f32_16x16x32_bf16(afrag[s], bv0, acc0, 0, 0, 0);
        acc1 = __builtin_amdgcn_mfma_f32_16x16x32_bf16(afrag[s], bv1, acc1, 0, 0, 0);
    }

    // C/D layout: row(oc within 16) = kg*4 + rr, col(pixel) = lane&15
    const int oc_c = wv * 16 + kg * 4;
    #pragma unroll
    for (int rr = 0; rr < 4; ++rr) {
        const float bb = bias[oc_c + rr];
        out[(b * OC + oc_c + rr) * NPIX + pp0] = acc0[rr] + bb;
        out[(b * OC + oc_c + rr) * NPIX + pp1] = acc1[rr] + bb;
    }
}

extern "C" void kernel_launch(void* const* d_in, const int* in_sizes, int n_in,
                              void* d_out, int out_size, void* d_ws, size_t ws_size,
                              hipStream_t stream) {
    const float* x    = (const float*)d_in[0];
    const float* w    = (const float*)d_in[1];
    const float* bias = (const float*)d_in[2];
    float* out        = (float*)d_out;

    unsigned short* xt = (unsigned short*)d_ws;
    unsigned short* wf = (unsigned short*)((char*)d_ws + XT_BYTES);

    hipLaunchKernelGGL(prep_x,   dim3(NB * HH + NB), dim3(256), 0, stream, x, xt);
    hipLaunchKernelGGL(repack_w, dim3(NS),           dim3(256), 0, stream, w, wf);
    hipLaunchKernelGGL(conv_main, dim3(NB * PT),     dim3(256), 0, stream,
                       xt, wf, bias, out);
}

// Round 3
// 68.947 us; speedup vs baseline: 1.2974x; 1.2974x over previous
//
#include <hip/hip_runtime.h>

// dissected Conv2d == standard 3x3 conv, NCHW, pad=1, fp32 in/out, bf16 MFMA.
// B=8, C_in=C_out=64, H=W=56.
//
// 2-launch pipeline:
//   1. repack_w:  w (OIHW fp32) -> bf16 MFMA A-frag layout [s][wv][lane][8]
//   2. conv_fused: 448 blocks (b x output-row) x 256 thr. Each block stages its
//      3-row input tile NCHW->bf16 into XOR-swizzled LDS, A-frags live in 72
//      VGPRs (one coalesced load each from packed wf), 72 MFMAs/wave.

typedef __attribute__((ext_vector_type(8))) short bf8_t;   // 8 bf16 (A/B frag)
typedef __attribute__((ext_vector_type(4))) float f4_t;    // C/D frag

#define IC 64
#define OC 64
#define HH 56
#define WW 56
#define NB 8
#define NS 18                  // K-steps of 32 (K = 9 taps * 64 ic, tap-major)
#define NPIX (HH * WW)
#define LCOLS 66               // LDS col dim: lc = input_col + 1, covers -1..64
#define LDS_U16 (3 * LCOLS * 64)   // 12672 u16 = 25344 B

__device__ __forceinline__ unsigned short f2bf(float f) {
    unsigned u = __float_as_uint(f);
    return (unsigned short)((u + 0x7FFFu + ((u >> 16) & 1u)) >> 16);
}

// ---------------------------------------------------------------------------
// Kernel 1: weights OIHW fp32 -> A-fragment bf16, layout [s][wv][lane][8].
// A-frag (16x16x32): lane holds A[row = lane&15][k = (lane>>4)*8 + j],
// global k = s*32 + klocal; k -> (tap = k/64, ic = k%64).  (verified in R2)
// ---------------------------------------------------------------------------
__global__ __launch_bounds__(256)
void repack_w(const float* __restrict__ w, unsigned short* __restrict__ wf) {
    const int s    = blockIdx.x;        // 0..17
    const int tid  = threadIdx.x;
    const int wv   = tid >> 6;
    const int lane = tid & 63;
    const int oc   = wv * 16 + (lane & 15);
    const int kg   = lane >> 4;
    const int tap  = s >> 1;
    const int ic0  = (s & 1) * 32 + kg * 8;
    unsigned short tmp[8];
    #pragma unroll
    for (int j = 0; j < 8; ++j)
        tmp[j] = f2bf(w[(oc * IC + ic0 + j) * 9 + tap]);
    *(uint4*)&wf[(((s * 4 + wv) * 64) + lane) * 8] = *(const uint4*)tmp;
}

// ---------------------------------------------------------------------------
// Kernel 2: fused conv. Grid 448 = 8 b x 56 rows, 256 thr (4 waves).
// Wave wv: oc [16wv,16wv+16), all 56 pixels of the row (4 MFMA N-tiles of 16,
// tile 3 partially masked). LDS x-tile [r3][lc66][ic64] bf16, XOR-swizzled:
//   byte S = Rrow*128 + ((chunk ^ (Rrow&7))<<4),  Rrow = r*66+lc, chunk = ic/8
// Swizzle is invariant under px += 16 (16 = 0 mod 8), so the 4 N-tiles are
// reached with immediate offsets +2048*t from one computed address.
// ---------------------------------------------------------------------------
__global__ __launch_bounds__(256)
void conv_fused(const float* __restrict__ x, const unsigned short* __restrict__ wf,
                const float* __restrict__ bias, float* __restrict__ out) {
    __shared__ unsigned short xl[LDS_U16];

    // XCD-chunked block swizzle (448 % 8 == 0 -> bijective): consecutive rows
    // land on the same XCD so halo rows hit that XCD's L2.
    int bid = (int)blockIdx.x;
    bid = (bid & 7) * (NB * HH / 8) + (bid >> 3);
    const int b = bid / HH;
    const int h = bid - b * HH;

    const int tid  = threadIdx.x;
    const int wv   = tid >> 6;
    const int lane = tid & 63;
    const int kg   = lane >> 4;
    const int l15  = lane & 15;

    // ---- A fragments: issue early, 18 coalesced 16B loads (L2-resident wf)
    bf8_t afrag[NS];
    #pragma unroll
    for (int s = 0; s < NS; ++s)
        afrag[s] = *(const bf8_t*)&wf[(((s * 4 + wv) * 64) + lane) * 8];

    // ---- zero the whole tile (linear b128 fill = conflict-free), so padding
    //      (lc==0, lc>=57, out-of-range rows) is zero without special cases
    for (int i = tid; i < LDS_U16 / 8; i += 256)
        ((uint4*)xl)[i] = uint4{0u, 0u, 0u, 0u};
    __syncthreads();

    // ---- stage x: 24 combos (icb(8) x r(3)); lane = lc, input col ci = lc-1
    {
        const int ci  = lane - 1;
        const bool cok = (ci >= 0) && (ci < WW);
        #pragma unroll
        for (int i = 0; i < 6; ++i) {
            const int combo = wv + 4 * i;          // 0..23
            const int icb = combo / 3;
            const int r   = combo - icb * 3;
            const int hh  = h - 1 + r;
            if (cok && hh >= 0 && hh < HH) {
                const float* src = &x[((b * IC + icb * 8) * HH + hh) * WW + ci];
                bf8_t v;
                #pragma unroll
                for (int j = 0; j < 8; ++j)
                    v[j] = (short)f2bf(src[j * HH * WW]);
                const int W = r * LCOLS + lane;    // 128B-row index
                const unsigned byte = (unsigned)W * 128u +
                                      ((unsigned)(icb ^ (W & 7)) << 4);
                *(bf8_t*)((char*)xl + byte) = v;
            }
        }
    }
    __syncthreads();

    // ---- K-loop: 18 steps x 4 pixel tiles
    f4_t acc[4];
    #pragma unroll
    for (int t = 0; t < 4; ++t) acc[t] = 0.f;

    #pragma unroll
    for (int s = 0; s < NS; ++s) {
        const int tap = s >> 1;
        const int dh  = tap / 3;
        const int dw  = tap - dh * 3;
        const int c   = (s & 1) * 4 + kg;              // 16B chunk index
        const int R0  = dh * LCOLS + dw + l15;         // row for tile 0 (lc=px+dw)
        const unsigned byte0 = (unsigned)R0 * 128u +
                               ((unsigned)(c ^ (R0 & 7)) << 4);
        const char* p = (const char*)xl + byte0;
        #pragma unroll
        for (int t = 0; t < 4; ++t) {
            const bf8_t bv = *(const bf8_t*)(p + t * 2048);
            acc[t] = __builtin_amdgcn_mfma_f32_16x16x32_bf16(afrag[s], bv, acc[t], 0, 0, 0);
        }
    }

    // ---- epilogue: C/D row = kg*4+rr (oc-local), col = l15 (pixel)
    const int oc_c = wv * 16 + kg * 4;
    float bb[4];
    #pragma unroll
    for (int rr = 0; rr < 4; ++rr) bb[rr] = bias[oc_c + rr];
    #pragma unroll
    for (int t = 0; t < 4; ++t) {
        const int px = t * 16 + l15;
        if (px < WW) {
            float* o = &out[((b * OC + oc_c) * HH + h) * WW + px];
            #pragma unroll
            for (int rr = 0; rr < 4; ++rr)
                o[rr * HH * WW] = acc[t][rr] + bb[rr];
        }
    }
}

extern "C" void kernel_launch(void* const* d_in, const int* in_sizes, int n_in,
                              void* d_out, int out_size, void* d_ws, size_t ws_size,
                              hipStream_t stream) {
    const float* x    = (const float*)d_in[0];
    const float* w    = (const float*)d_in[1];
    const float* bias = (const float*)d_in[2];
    float* out        = (float*)d_out;

    unsigned short* wf = (unsigned short*)d_ws;   // 73,728 B packed A-frags

    hipLaunchKernelGGL(repack_w,  dim3(NS),      dim3(256), 0, stream, w, wf);
    hipLaunchKernelGGL(conv_fused, dim3(NB * HH), dim3(256), 0, stream,
                       x, wf, bias, out);
}

// Round 4
// 68.459 us; speedup vs baseline: 1.3067x; 1.0071x over previous
//
#include <hip/hip_runtime.h>

// dissected Conv2d == standard 3x3 conv, NCHW, pad=1, fp32 in/out, bf16 MFMA.
// B=8, C_in=C_out=64, H=W=56.
//
// 2-launch pipeline:
//   1. repack_w:  w (OIHW fp32) -> bf16 MFMA A-frag layout [s][wv][lane][8]
//   2. conv_half: 896 blocks (b x row x half-row) x 256 thr (4 waves).
//      Each block stages a 3-row x 30-col x 64-ic input patch NCHW->bf16 into
//      XOR-swizzled LDS (13 KB), A-frags in 72 VGPRs, 36 MFMAs/wave.
//      3.5 waves/SIMD occupancy; single barrier; predicated-zero staging
//      (no LDS pre-zero pass).

typedef __attribute__((ext_vector_type(8))) short bf8_t;   // 8 bf16 (A/B frag)
typedef __attribute__((ext_vector_type(4))) float f4_t;    // C/D frag

#define IC 64
#define OC 64
#define HH 56
#define WW 56
#define NB 8
#define NS 18                  // K-steps of 32 (K = 9 taps * 64 ic, tap-major)
#define NPIX (HH * WW)
#define LC34 34                // LDS col dim (30 used + 4 garbage-pad for reads)
#define LDS_U16 (3 * LC34 * 64)    // 6528 u16 = 13056 B

__device__ __forceinline__ unsigned short f2bf(float f) {
    unsigned u = __float_as_uint(f);
    return (unsigned short)((u + 0x7FFFu + ((u >> 16) & 1u)) >> 16);
}

// ---------------------------------------------------------------------------
// Kernel 1: weights OIHW fp32 -> A-fragment bf16, layout [s][wv][lane][8].
// A-frag (16x16x32): lane holds A[row = lane&15][k = (lane>>4)*8 + j],
// global k = s*32 + klocal; k -> (tap = k/64, ic = k%64).  (verified R2/R3)
// ---------------------------------------------------------------------------
__global__ __launch_bounds__(256)
void repack_w(const float* __restrict__ w, unsigned short* __restrict__ wf) {
    const int s    = blockIdx.x;        // 0..17
    const int tid  = threadIdx.x;
    const int wv   = tid >> 6;
    const int lane = tid & 63;
    const int oc   = wv * 16 + (lane & 15);
    const int kg   = lane >> 4;
    const int tap  = s >> 1;
    const int ic0  = (s & 1) * 32 + kg * 8;
    unsigned short tmp[8];
    #pragma unroll
    for (int j = 0; j < 8; ++j)
        tmp[j] = f2bf(w[(oc * IC + ic0 + j) * 9 + tap]);
    *(uint4*)&wf[(((s * 4 + wv) * 64) + lane) * 8] = *(const uint4*)tmp;
}

// ---------------------------------------------------------------------------
// Kernel 2: fused conv, half-row blocks. Grid 896 = 8 b x 56 h x 2 ph.
// Wave wv: oc [16wv,16wv+16), 28 px of this half (2 MFMA N-tiles, tile 1
// masked to 12 lanes). LDS x-patch [r3][lc34][ic64] bf16, XOR-swizzled:
//   byte = W*128 + ((icb ^ (W&7))<<4),  W = r*34+lc, icb = 16B ic-chunk.
// lc = local col; input col ci = ph*28 - 1 + lc (lc 0..29 staged; 30..33
// garbage, feeds only epilogue-masked MFMA columns). Swizzle invariant under
// lc += 16, so N-tile 1 is +2048 B from tile 0's address.
// ---------------------------------------------------------------------------
__global__ __launch_bounds__(256)
void conv_half(const float* __restrict__ x, const unsigned short* __restrict__ wf,
               const float* __restrict__ bias, float* __restrict__ out) {
    __shared__ unsigned short xl[LDS_U16];

    // XCD-chunked bijective swizzle (896 % 8 == 0): consecutive (h, ph) land
    // on one XCD so shared halo rows hit that XCD's L2.
    int bid = (int)blockIdx.x;
    bid = (bid & 7) * (NB * HH * 2 / 8) + (bid >> 3);
    const int b   = bid / (HH * 2);
    const int rem = bid - b * (HH * 2);
    const int h   = rem >> 1;
    const int ph  = rem & 1;

    const int tid  = threadIdx.x;
    const int wv   = tid >> 6;
    const int lane = tid & 63;
    const int kg   = lane >> 4;
    const int l15  = lane & 15;

    // ---- A fragments: issue early, 18 coalesced 16B loads (L2-resident wf)
    bf8_t afrag[NS];
    #pragma unroll
    for (int s = 0; s < NS; ++s)
        afrag[s] = *(const bf8_t*)&wf[(((s * 4 + wv) * 64) + lane) * 8];

    // ---- stage x: 24 combos (icb8 x r3), 2 per instruction via lane halves.
    //      Loads first (one vmcnt drain), then cvt+pack+swizzled b128 writes.
    const int half = lane >> 5;
    const int lc   = lane & 31;
    const int ci   = ph * 28 - 1 + lc;
    const bool doW = (lc < 30);
    const bool cok = doW && (ci >= 0) && (ci < WW);

    float rv[3][8];
    #pragma unroll
    for (int i = 0; i < 3; ++i) {
        const int c   = wv * 6 + 2 * i + half;   // 0..23
        const int icb = c / 3;
        const int r   = c - 3 * icb;
        const int hh  = h - 1 + r;
        const bool ok = cok && (hh >= 0) && (hh < HH);
        const float* src = &x[((b * IC + icb * 8) * HH + hh) * WW + ci];
        #pragma unroll
        for (int j = 0; j < 8; ++j)
            rv[i][j] = ok ? src[j * HH * WW] : 0.f;
    }
    #pragma unroll
    for (int i = 0; i < 3; ++i) {
        const int c   = wv * 6 + 2 * i + half;
        const int icb = c / 3;
        const int r   = c - 3 * icb;
        bf8_t v;
        #pragma unroll
        for (int j = 0; j < 8; ++j) v[j] = (short)f2bf(rv[i][j]);
        const int W = r * LC34 + lc;
        const unsigned byte = (unsigned)W * 128u +
                              ((unsigned)(icb ^ (W & 7)) << 4);
        if (doW) *(bf8_t*)((char*)xl + byte) = v;
    }
    __syncthreads();

    // ---- K-loop: 18 steps x 2 pixel tiles
    f4_t acc0 = {0.f, 0.f, 0.f, 0.f};
    f4_t acc1 = {0.f, 0.f, 0.f, 0.f};
    #pragma unroll
    for (int s = 0; s < NS; ++s) {
        const int tap = s >> 1;
        const int dh  = tap / 3;
        const int dw  = tap - dh * 3;
        const int c16 = (s & 1) * 4 + kg;              // 16B ic-chunk
        const int W0  = dh * LC34 + dw + l15;          // row for tile 0
        const unsigned byte0 = (unsigned)W0 * 128u +
                               ((unsigned)(c16 ^ (W0 & 7)) << 4);
        const char* p = (const char*)xl + byte0;
        const bf8_t bv0 = *(const bf8_t*)p;
        const bf8_t bv1 = *(const bf8_t*)(p + 2048);   // lc += 16, same XOR
        acc0 = __builtin_amdgcn_mfma_f32_16x16x32_bf16(afrag[s], bv0, acc0, 0, 0, 0);
        acc1 = __builtin_amdgcn_mfma_f32_16x16x32_bf16(afrag[s], bv1, acc1, 0, 0, 0);
    }

    // ---- epilogue: C/D row = kg*4+rr (oc-local), col = l15 (pixel)
    const int oc_c = wv * 16 + kg * 4;
    float bb[4];
    #pragma unroll
    for (int rr = 0; rr < 4; ++rr) bb[rr] = bias[oc_c + rr];
    {
        const int px = ph * 28 + l15;                  // tile 0: always valid
        float* o = &out[((b * OC + oc_c) * HH + h) * WW + px];
        #pragma unroll
        for (int rr = 0; rr < 4; ++rr)
            o[rr * NPIX] = acc0[rr] + bb[rr];
    }
    if (l15 < 12) {                                    // tile 1: px_local 16..27
        const int px = ph * 28 + 16 + l15;
        float* o = &out[((b * OC + oc_c) * HH + h) * WW + px];
        #pragma unroll
        for (int rr = 0; rr < 4; ++rr)
            o[rr * NPIX] = acc1[rr] + bb[rr];
    }
}

extern "C" void kernel_launch(void* const* d_in, const int* in_sizes, int n_in,
                              void* d_out, int out_size, void* d_ws, size_t ws_size,
                              hipStream_t stream) {
    const float* x    = (const float*)d_in[0];
    const float* w    = (const float*)d_in[1];
    const float* bias = (const float*)d_in[2];
    float* out        = (float*)d_out;

    unsigned short* wf = (unsigned short*)d_ws;   // 73,728 B packed A-frags

    hipLaunchKernelGGL(repack_w,  dim3(NS),          dim3(256), 0, stream, w, wf);
    hipLaunchKernelGGL(conv_half, dim3(NB * HH * 2), dim3(256), 0, stream,
                       x, wf, bias, out);
}